// Round 12
// baseline (137.462 us; speedup 1.0000x reference)
//
#include <hip/hip_runtime.h>
#include <math.h>

typedef _Float16 f16;
typedef __attribute__((ext_vector_type(2))) _Float16 f16x2;
typedef __attribute__((ext_vector_type(4))) _Float16 f16x4;
typedef __attribute__((ext_vector_type(8))) _Float16 f16x8;
typedef __attribute__((ext_vector_type(4))) float f32x4;

#define NBATCH 8
#define WSA_ELE 36864      // 32*1152 (w_off padded to 32 rows, k-major, frag-swizzled)
#define WSB_ELE 147456     // 128*1152 (w_def, k-major, frag-swizzled)
#define PREP_BLOCKS 720    // (WSA_ELE + WSB_ELE) / 256
// workspace byte offsets
#define OFF_WSB  73728
#define OFF_XT   368640

// dynamic LDS layout (bytes)
#define A_OFF     0        // 72 KB: A quarter (9 chunks x 8 mt x 512 f16)
#define B_OFF     73728    // 36 KB: packed sampled-B (9 chunks x 64 px x 4 slots x 16B)
#define OFS_OFF   110592   // 9.2 KB: corner byte-offsets
#define WTH_OFF   119808   // 4.6 KB: packed f16 bilinear weights
#define SOFF_OFF  124416   // 7 KB: offset-conv row (phases 1-2 only)
#define SMEM_BYTES 131456

__device__ __forceinline__ void gload_lds16(const f16* gsrc, f16* ldst) {
  // global source is PER-LANE (+lane*8 f16); LDS dest is wave-uniform base,
  // HW adds lane*16 bytes.
  __builtin_amdgcn_global_load_lds(
      (const __attribute__((address_space(1))) unsigned int*)gsrc,
      (__attribute__((address_space(3))) unsigned int*)ldst, 16, 0, 0);
}

// ---------------- merged prep (weights -> fp16 frag-swizzled) + transpose ----------------
__global__ __launch_bounds__(256) void prep_transpose_kernel(const float* __restrict__ w_off,
                                                             const float* __restrict__ w_def,
                                                             f16* __restrict__ wsA,
                                                             f16* __restrict__ wsB,
                                                             const float* __restrict__ x,
                                                             f16* __restrict__ xt) {
  __shared__ __align__(16) f16 s_t[128 * 68];   // pitch 68: 8B-aligned rows
  const int t = threadIdx.x;
  if (blockIdx.x < PREP_BLOCKS) {
    int i = blockIdx.x * 256 + t;
    if (i < WSA_ELE) {
      int j = i & 7, lane = (i >> 3) & 63, fm = i >> 9;
      int ch = fm >> 1, mt = fm & 1;
      int row = mt * 16 + (lane & 15);
      int kidx = ch * 32 + (lane >> 4) * 8 + j;
      int k = kidx >> 7, cc = kidx & 127;
      float v = (row < 27) ? w_off[row * 1152 + cc * 9 + k] : 0.0f;
      wsA[i] = (f16)v;
    } else {
      int e = i - WSA_ELE;
      int j = e & 7, lane = (e >> 3) & 63, fm = e >> 9;
      int ch = fm >> 3, mt = fm & 7;
      int row = mt * 16 + (lane & 15);
      int kidx = ch * 32 + (lane >> 4) * 8 + j;
      int k = kidx >> 7, cc = kidx & 127;
      wsB[e] = (f16)w_def[row * 1152 + cc * 9 + k];
    }
    return;
  }
  const int bid = blockIdx.x - PREP_BLOCKS;
  const int b = bid >> 6;
  const int pos0 = (bid & 63) << 6;
  const float* xb = x + ((size_t)b << 19);
  #pragma unroll
  for (int it = 0; it < 8; ++it) {
    int i = it * 256 + t;
    int c = i >> 4, p4 = (i & 15) << 2;
    float4 v = *(const float4*)&xb[c * 4096 + pos0 + p4];
    f16x4 h = {(f16)v.x, (f16)v.y, (f16)v.z, (f16)v.w};
    *(f16x4*)&s_t[c * 68 + p4] = h;
  }
  __syncthreads();
  f16* xtb = xt + ((size_t)b << 19);
  #pragma unroll
  for (int it = 0; it < 8; ++it) {
    int i = it * 256 + t;
    int p = i >> 5, c4 = (i & 31) << 2;
    f16x4 h = {s_t[(c4    ) * 68 + p],
               s_t[(c4 + 1) * 68 + p],
               s_t[(c4 + 2) * 68 + p],
               s_t[(c4 + 3) * 68 + p]};
    *(f16x4*)&xtb[(size_t)(pos0 + p) * 128 + c4] = h;
  }
}

// ---------------- fused DCN: materialize-then-GEMM, wave-role split ----------------
// 512 threads / 8 waves, one (b,ho) row per block, 1 block/CU (131 KB LDS).
// K split into 4 quarters of 9 chunks. Per quarter:
//   3a: waves 0-3 run ALL 36 gathers+packs back-to-back (deep VMEM pipeline, no
//       MFMA/barriers interleaved) and ds_write packed B to s_b; waves 4-7
//       concurrently stage the 72 KB A-quarter via gload_lds.  __syncthreads.
//   3b: all 8 waves: 9 chunks of pure LDS GEMM (1 B-read + 4 A-reads + 4 MFMA),
//       ZERO VMEM, ZERO barriers.  __syncthreads.
// oc split across wave groups: mtg = wid>>2 owns mt 4*mtg..4*mtg+3.
__global__ __launch_bounds__(512, 1) void fused_dcn_kernel(const f16* __restrict__ xt,
                                                           const f16* __restrict__ wsA,
                                                           const f16* __restrict__ wsB,
                                                           const float* __restrict__ b_off,
                                                           const float* __restrict__ b_def,
                                                           float* __restrict__ out) {
  extern __shared__ __align__(16) char smem[];
  f16*   s_a   = (f16*)(smem + A_OFF);
  f16*   s_b   = (f16*)(smem + B_OFF);
  uint4* s_ofs = (uint4*)(smem + OFS_OFF);
  f16x4* s_wth = (f16x4*)(smem + WTH_OFF);
  float* s_off = (float*)(smem + SOFF_OFF);

  const int t = threadIdx.x;
  const int b = blockIdx.x & 7, ho = blockIdx.x >> 3;   // XCD = batch
  const int lane = t & 63, wid = t >> 6;
  const int q = lane >> 4, li = lane & 15;
  const int px = ((wid & 3) << 4) + li;
  const int mtg = wid >> 2;                             // 0: producer, 1: stager
  const char* xtb = (const char*)xt + ((size_t)b << 20);

  if (mtg == 1) {
    // pre-stage A quarter 0 (72 segs of 512 f16; this wave takes 18)
    const int s0 = (wid - 4) * 18;
    #pragma unroll
    for (int j = 0; j < 18; ++j)
      gload_lds16(wsB + (s0 + j) * 512 + lane * 8, s_a + (s0 + j) * 512);
  } else {
    // ---- phase 1: offset conv, M=32 (27 live rows), im2col MFMA (waves 0-3) ----
    f32x4 acc0 = {0.f, 0.f, 0.f, 0.f}, acc1 = {0.f, 0.f, 0.f, 0.f};
    #pragma unroll
    for (int k = 0; k < 9; ++k) {
      const int ky = k / 3, kx = k - ky * 3;
      const int y = ho + ky - 1;
      const int xx = px + kx - 1;
      const bool valid = ((unsigned)y < 64u) && ((unsigned)xx < 64u);
      const int pos = min(max(y, 0), 63) * 64 + min(max(xx, 0), 63);
      const int voff = pos * 256 + q * 16;
      #pragma unroll
      for (int c4 = 0; c4 < 4; ++c4) {
        union { uint4 u; f16x8 v; } bu;
        bu.u = *(const uint4*)(xtb + voff + c4 * 64);
        if (!valid) { bu.u.x = 0u; bu.u.y = 0u; bu.u.z = 0u; bu.u.w = 0u; }
        const int ch = k * 4 + c4;
        f16x8 a0 = *(const f16x8*)&wsA[(ch * 2    ) * 512 + lane * 8];
        f16x8 a1 = *(const f16x8*)&wsA[(ch * 2 + 1) * 512 + lane * 8];
        acc0 = __builtin_amdgcn_mfma_f32_16x16x32_f16(a0, bu.v, acc0, 0, 0, 0);
        acc1 = __builtin_amdgcn_mfma_f32_16x16x32_f16(a1, bu.v, acc1, 0, 0, 0);
      }
    }
    #pragma unroll
    for (int mt = 0; mt < 2; ++mt) {
      f32x4 a = mt ? acc1 : acc0;
      #pragma unroll
      for (int r = 0; r < 4; ++r) {
        int oc = mt * 16 + q * 4 + r;
        if (oc < 27) {
          float v = a[r] + b_off[oc];
          if (oc >= 18) v = 1.0f / (1.0f + __expf(-v));
          s_off[oc * 65 + px] = v;
        }
      }
    }
  }
  __syncthreads();   // offset row ready + A(0) staged

  // ---- phase 2: bilinear table (all 8 waves) ----
  for (int f = t; f < 576; f += 512) {
    int k = f >> 6, p = f & 63;
    int ky = k / 3, kx = k - ky * 3;
    float oy = s_off[(2 * k    ) * 65 + p];
    float ox = s_off[(2 * k + 1) * 65 + p];
    float m  = s_off[(18 + k   ) * 65 + p];
    float py  = oy + (float)(ho + ky - 1);
    float pxf = ox + (float)(p + kx - 1);
    float y0f = floorf(py), x0f = floorf(pxf);
    float wy = py - y0f, wx = pxf - x0f;
    int y0 = (int)y0f, x0 = (int)x0f;
    int y1 = y0 + 1, x1 = x0 + 1;
    bool y0v = (unsigned)y0 < 64u, y1v = (unsigned)y1 < 64u;
    bool x0v = (unsigned)x0 < 64u, x1v = (unsigned)x1 < 64u;
    int y0c = min(max(y0, 0), 63), y1c = min(max(y1, 0), 63);
    int x0c = min(max(x0, 0), 63), x1c = min(max(x1, 0), 63);
    uint4 o4;
    o4.x = (unsigned)((y0c * 64 + x0c) * 256);
    o4.y = (unsigned)((y0c * 64 + x1c) * 256);
    o4.z = (unsigned)((y1c * 64 + x0c) * 256);
    o4.w = (unsigned)((y1c * 64 + x1c) * 256);
    float w0 = (y0v && x0v) ? (1.f - wy) * (1.f - wx) * m : 0.f;
    float w1 = (y0v && x1v) ? (1.f - wy) * wx         * m : 0.f;
    float w2 = (y1v && x0v) ? wy         * (1.f - wx) * m : 0.f;
    float w3 = (y1v && x1v) ? wy         * wx         * m : 0.f;
    s_ofs[f] = o4;
    f16x4 wp = {(f16)w0, (f16)w1, (f16)w2, (f16)w3};
    s_wth[f] = wp;
  }
  __syncthreads();   // tables ready

  // ---- phase 3: 4 quarters of {materialize B + stage A} -> {pure LDS GEMM} ----
  f32x4 acc[4];
  #pragma unroll
  for (int m = 0; m < 4; ++m) acc[m] = (f32x4){0.f, 0.f, 0.f, 0.f};

  const int slot = (q ^ (px & 3));   // s_b bank swizzle (write == read)

  for (int Q = 0; Q < 4; ++Q) {
    // ---- 3a ----
    if (mtg == 1) {
      if (Q > 0) {
        const int s0 = (wid - 4) * 18;
        #pragma unroll
        for (int j = 0; j < 18; ++j)
          gload_lds16(wsB + (Q * 72 + s0 + j) * 512 + lane * 8, s_a + (s0 + j) * 512);
      }
    } else {
      #pragma unroll
      for (int c = 0; c < 9; ++c) {
        const int ch = Q * 9 + c;
        const int k = ch >> 2, c4 = ch & 3;
        const uint4 o4 = s_ofs[k * 64 + px];
        const f16x4 wp = s_wth[k * 64 + px];
        const unsigned add = q * 16 + c4 * 64;
        union { uint4 u; f16x2 h[4]; } d0, d1, d2, d3;
        d0.u = *(const uint4*)(xtb + o4.x + add);
        d1.u = *(const uint4*)(xtb + o4.y + add);
        d2.u = *(const uint4*)(xtb + o4.z + add);
        d3.u = *(const uint4*)(xtb + o4.w + add);
        const f16x2 wp0 = {wp.x, wp.x}, wp1 = {wp.y, wp.y};
        const f16x2 wp2 = {wp.z, wp.z}, wp3 = {wp.w, wp.w};
        union { f16x2 h[4]; uint4 u; } bf;
        #pragma unroll
        for (int i = 0; i < 4; ++i) {
          f16x2 s = d0.h[i] * wp0;
          s = s + d1.h[i] * wp1;
          s = s + d2.h[i] * wp2;
          s = s + d3.h[i] * wp3;
          bf.h[i] = s;
        }
        *(uint4*)&s_b[c * 2048 + px * 32 + slot * 8] = bf.u;
      }
    }
    __syncthreads();   // A(Q) + B(Q) ready (full drain, once per quarter)

    // ---- 3b: 9 chunks of pure LDS GEMM, no VMEM, no barriers ----
    #pragma unroll
    for (int c = 0; c < 9; ++c) {
      union { uint4 u; f16x8 v; } bf;
      bf.u = *(const uint4*)&s_b[c * 2048 + px * 32 + slot * 8];
      const f16* ab = s_a + (c * 8 + mtg * 4) * 512;
      #pragma unroll
      for (int m = 0; m < 4; ++m) {
        f16x8 a = *(const f16x8*)&ab[m * 512 + lane * 8];
        acc[m] = __builtin_amdgcn_mfma_f32_16x16x32_f16(a, bf.v, acc[m], 0, 0, 0);
      }
    }
    __syncthreads();   // protect s_a/s_b overwrite by next quarter's 3a
  }

  float* o = out + (size_t)b * 128 * 4096 + ho * 64 + px;
  #pragma unroll
  for (int m = 0; m < 4; ++m) {
    #pragma unroll
    for (int r = 0; r < 4; ++r) {
      int oc = (mtg * 4 + m) * 16 + q * 4 + r;
      o[oc * 4096] = acc[m][r] + b_def[oc];
    }
  }
}

extern "C" void kernel_launch(void* const* d_in, const int* in_sizes, int n_in,
                              void* d_out, int out_size, void* d_ws, size_t ws_size,
                              hipStream_t stream) {
  const float* x     = (const float*)d_in[0];
  const float* w_off = (const float*)d_in[1];
  const float* b_off = (const float*)d_in[2];
  const float* w_def = (const float*)d_in[3];
  const float* b_def = (const float*)d_in[4];
  float* out = (float*)d_out;

  f16* wsA = (f16*)d_ws;
  f16* wsB = (f16*)((char*)d_ws + OFF_WSB);
  f16* xt  = (f16*)((char*)d_ws + OFF_XT);

  static int smem_opted = 0;
  if (!smem_opted) {
    hipFuncSetAttribute((const void*)fused_dcn_kernel,
                        hipFuncAttributeMaxDynamicSharedMemorySize, SMEM_BYTES);
    smem_opted = 1;
  }

  prep_transpose_kernel<<<dim3(PREP_BLOCKS + NBATCH * 64), dim3(256), 0, stream>>>(
      w_off, w_def, wsA, wsB, x, xt);
  fused_dcn_kernel<<<dim3(NBATCH * 64), dim3(512), SMEM_BYTES, stream>>>(
      xt, wsA, wsB, b_off, b_def, out);
}

// Round 13
// 111.732 us; speedup vs baseline: 1.2303x; 1.2303x over previous
//
#include <hip/hip_runtime.h>
#include <math.h>

typedef _Float16 f16;
typedef __attribute__((ext_vector_type(2))) _Float16 f16x2;
typedef __attribute__((ext_vector_type(4))) _Float16 f16x4;
typedef __attribute__((ext_vector_type(8))) _Float16 f16x8;
typedef __attribute__((ext_vector_type(4))) float f32x4;

#define NBATCH 8
#define WSA_ELE 36864      // 32*1152 (w_off padded to 32 rows, k-major, frag-swizzled)
#define WSB_ELE 147456     // 128*1152 (w_def, k-major, frag-swizzled)
#define PREP_BLOCKS 720    // (WSA_ELE + WSB_ELE) / 256
// workspace byte offsets
#define OFF_WSB  73728
#define OFF_XT   368640

// dynamic LDS layout (bytes)
#define WIN_OFF    0        // 128 KB: 8-row x-window, pixel-slot XOR-swizzled
#define A_OFF      131072   // 16 KB: A chunk double-buffer (2 x 4096 f16)
#define SOFF_OFF   147456   // 14 KB: 2 x 27x65 offset-conv rows
#define SMEM_BYTES 161536

__device__ __forceinline__ void gload_lds16(const f16* gsrc, f16* ldst) {
  // global source is PER-LANE (+lane*8 f16); LDS dest is wave-uniform base,
  // HW adds lane*16 bytes.  (R9 lesson: never drop the lane term on src.)
  __builtin_amdgcn_global_load_lds(
      (const __attribute__((address_space(1))) unsigned int*)gsrc,
      (__attribute__((address_space(3))) unsigned int*)ldst, 16, 0, 0);
}

// ---------------- merged prep (weights -> fp16 frag-swizzled) + transpose ----------------
__global__ __launch_bounds__(256) void prep_transpose_kernel(const float* __restrict__ w_off,
                                                             const float* __restrict__ w_def,
                                                             f16* __restrict__ wsA,
                                                             f16* __restrict__ wsB,
                                                             const float* __restrict__ x,
                                                             f16* __restrict__ xt) {
  __shared__ __align__(16) f16 s_t[128 * 68];   // pitch 68: 8B-aligned rows
  const int t = threadIdx.x;
  if (blockIdx.x < PREP_BLOCKS) {
    int i = blockIdx.x * 256 + t;
    if (i < WSA_ELE) {
      int j = i & 7, lane = (i >> 3) & 63, fm = i >> 9;
      int ch = fm >> 1, mt = fm & 1;
      int row = mt * 16 + (lane & 15);
      int kidx = ch * 32 + (lane >> 4) * 8 + j;
      int k = kidx >> 7, cc = kidx & 127;
      float v = (row < 27) ? w_off[row * 1152 + cc * 9 + k] : 0.0f;
      wsA[i] = (f16)v;
    } else {
      int e = i - WSA_ELE;
      int j = e & 7, lane = (e >> 3) & 63, fm = e >> 9;
      int ch = fm >> 3, mt = fm & 7;
      int row = mt * 16 + (lane & 15);
      int kidx = ch * 32 + (lane >> 4) * 8 + j;
      int k = kidx >> 7, cc = kidx & 127;
      wsB[e] = (f16)w_def[row * 1152 + cc * 9 + k];
    }
    return;
  }
  const int bid = blockIdx.x - PREP_BLOCKS;
  const int b = bid >> 6;
  const int pos0 = (bid & 63) << 6;
  const float* xb = x + ((size_t)b << 19);
  #pragma unroll
  for (int it = 0; it < 8; ++it) {
    int i = it * 256 + t;
    int c = i >> 4, p4 = (i & 15) << 2;
    float4 v = *(const float4*)&xb[c * 4096 + pos0 + p4];
    f16x4 h = {(f16)v.x, (f16)v.y, (f16)v.z, (f16)v.w};
    *(f16x4*)&s_t[c * 68 + p4] = h;
  }
  __syncthreads();
  f16* xtb = xt + ((size_t)b << 19);
  #pragma unroll
  for (int it = 0; it < 8; ++it) {
    int i = it * 256 + t;
    int p = i >> 5, c4 = (i & 31) << 2;
    f16x4 h = {s_t[(c4    ) * 68 + p],
               s_t[(c4 + 1) * 68 + p],
               s_t[(c4 + 2) * 68 + p],
               s_t[(c4 + 3) * 68 + p]};
    *(f16x4*)&xtb[(size_t)(pos0 + p) * 128 + c4] = h;
  }
}

// ---------------- fused DCN: 2-row block + LDS x-window (TA-free gathers) ----------------
// One 512-thread block per (b, row-pair hp); grid 256 = 1 block/CU, ONE round.
// Waves 0-3 own row 2hp, waves 4-7 own row 2hp+1 (each wave: 16 px, all 8 mt).
// The 8-row window [2hp-3, 2hp+4] (128 KB) is staged ONCE, coalesced (8 lines/KB
// vs 16 for the scattered gathers) and serves BOTH rows + phase-1 im2col.
// All corner reads become ds_read_b128 with the R6-verified pixel-slot XOR
// swizzle -> the texture-addresser (the 12-round-invariant bottleneck: ~16
// lines/instr on every scattered VMEM op) is out of the main loop entirely.
// Bilinear tables live in REGISTERS (per-lane, constant-indexed via full unroll).
__global__ __launch_bounds__(512, 1) void fused_dcn_kernel(const f16* __restrict__ xt,
                                                           const f16* __restrict__ wsA,
                                                           const f16* __restrict__ wsB,
                                                           const float* __restrict__ b_off,
                                                           const float* __restrict__ b_def,
                                                           float* __restrict__ out) {
  extern __shared__ __align__(16) char smem[];
  char*  win      = smem;
  f16*   s_a      = (f16*)(smem + A_OFF);
  float* s_offall = (float*)(smem + SOFF_OFF);

  const int t = threadIdx.x;
  const int b = blockIdx.x & 7;                 // XCD = batch
  const int hp = blockIdx.x >> 3;               // row pair 0..31
  const int lane = t & 63, wid = t >> 6;
  const int row = wid >> 2;                     // 0 or 1
  const int rowy = hp * 2 + row;
  const int q = lane >> 4, li = lane & 15;
  const int px = ((wid & 3) << 4) + li;
  const char* xtb = (const char*)xt + ((size_t)b << 20);
  const int y_lo = max(hp * 2 - 3, 0);
  const int y_hi = min(hp * 2 + 4, 63);

  // ---- phase 0: stage x-window rows [y_lo, y_hi] (coalesced, slot-swizzled) ----
  {
    const int nunits = (y_hi - y_lo + 1) << 10;   // 16B units: rows*64px*16
    for (int u = t; u < nunits; u += 512) {
      const int r = u >> 10, rem = u & 1023;
      const int xx = rem >> 4, s = rem & 15;
      const int qq = s & 3, cc4 = s >> 2;
      const uint4 v = *(const uint4*)(xtb + ((((y_lo + r) * 64 + xx) << 8) + (cc4 << 6) + (qq << 4)));
      const int s1 = xx & 3, s2 = (xx >> 2) & 1;
      *(uint4*)(win + (((r * 64 + xx) << 8) + ((qq ^ s1) << 4) + ((cc4 ^ s2) << 6))) = v;
    }
  }
  __syncthreads();   // window ready

  // ---- phase 1: offset conv for this wave's row (taps from window) ----
  {
    float* so = s_offall + row * (27 * 65);
    f32x4 acc0 = {0.f, 0.f, 0.f, 0.f}, acc1 = {0.f, 0.f, 0.f, 0.f};
    #pragma unroll
    for (int k = 0; k < 9; ++k) {
      const int ky = k / 3, kx = k - ky * 3;
      const int y = rowy + ky - 1;
      const int xx = px + kx - 1;
      const bool valid = ((unsigned)y < 64u) && ((unsigned)xx < 64u);
      const int yc = min(max(y, y_lo), y_hi);
      const int xc = min(max(xx, 0), 63);
      const int base = (((yc - y_lo) * 64 + xc) << 8) + ((q ^ (xc & 3)) << 4) + ((((xc >> 2) & 1)) << 6);
      #pragma unroll
      for (int c4 = 0; c4 < 4; ++c4) {
        union { uint4 u; f16x8 v; } bu;
        bu.u = *(const uint4*)(win + (base ^ (c4 << 6)));
        if (!valid) { bu.u.x = 0u; bu.u.y = 0u; bu.u.z = 0u; bu.u.w = 0u; }
        const int ch = k * 4 + c4;
        f16x8 a0 = *(const f16x8*)&wsA[(ch * 2    ) * 512 + lane * 8];
        f16x8 a1 = *(const f16x8*)&wsA[(ch * 2 + 1) * 512 + lane * 8];
        acc0 = __builtin_amdgcn_mfma_f32_16x16x32_f16(a0, bu.v, acc0, 0, 0, 0);
        acc1 = __builtin_amdgcn_mfma_f32_16x16x32_f16(a1, bu.v, acc1, 0, 0, 0);
      }
    }
    #pragma unroll
    for (int mt = 0; mt < 2; ++mt) {
      f32x4 a = mt ? acc1 : acc0;
      #pragma unroll
      for (int r = 0; r < 4; ++r) {
        int oc = mt * 16 + q * 4 + r;
        if (oc < 27) {
          float v = a[r] + b_off[oc];
          if (oc >= 18) v = 1.0f / (1.0f + __expf(-v));
          so[oc * 65 + px] = v;
        }
      }
    }
  }
  __syncthreads();   // offset rows ready

  // ---- phase 2: per-lane bilinear tables in REGISTERS (window-slot indices) ----
  unsigned posA[9], posB[9];   // packed (i00|i01<<16), (i10|i11<<16); idx = slot*64+x
  f16x4 wts[9];
  {
    const float* so = s_offall + row * (27 * 65);
    #pragma unroll
    for (int k = 0; k < 9; ++k) {
      const int ky = k / 3, kx = k - ky * 3;
      float oy = so[(2 * k    ) * 65 + px];
      float ox = so[(2 * k + 1) * 65 + px];
      float m  = so[(18 + k   ) * 65 + px];
      float py  = oy + (float)(rowy + ky - 1);
      float pxf = ox + (float)(px + kx - 1);
      float y0f = floorf(py), x0f = floorf(pxf);
      float wy = py - y0f, wx = pxf - x0f;
      int y0 = (int)y0f, x0 = (int)x0f;
      bool y0v = (unsigned)y0 < 64u, y1v = (unsigned)(y0 + 1) < 64u;
      bool x0v = (unsigned)x0 < 64u, x1v = (unsigned)(x0 + 1) < 64u;
      int y0a = min(max(y0, y_lo), y_hi), y1a = min(max(y0 + 1, y_lo), y_hi);
      int x0c = min(max(x0, 0), 63),      x1c = min(max(x0 + 1, 0), 63);
      unsigned i00 = (unsigned)((y0a - y_lo) * 64 + x0c);
      unsigned i01 = (unsigned)((y0a - y_lo) * 64 + x1c);
      unsigned i10 = (unsigned)((y1a - y_lo) * 64 + x0c);
      unsigned i11 = (unsigned)((y1a - y_lo) * 64 + x1c);
      posA[k] = i00 | (i01 << 16);
      posB[k] = i10 | (i11 << 16);
      float w0 = (y0v && x0v) ? (1.f - wy) * (1.f - wx) * m : 0.f;
      float w1 = (y0v && x1v) ? (1.f - wy) * wx         * m : 0.f;
      float w2 = (y1v && x0v) ? wy         * (1.f - wx) * m : 0.f;
      float w3 = (y1v && x1v) ? wy         * wx         * m : 0.f;
      f16x4 wp = {(f16)w0, (f16)w1, (f16)w2, (f16)w3};
      wts[k] = wp;
    }
  }

  // stage A(0) (1 gload/wave); the barrier drains it (per-wave vmcnt before s_barrier)
  gload_lds16(wsB + wid * 512 + lane * 8, s_a + wid * 512);
  __syncthreads();

  // ---- phase 3: 36 chunks, corners via ds_read from window, A via LDS dbuf ----
  f32x4 acc[8];
  #pragma unroll
  for (int mt = 0; mt < 8; ++mt) acc[mt] = (f32x4){0.f, 0.f, 0.f, 0.f};

  #pragma unroll
  for (int k = 0; k < 9; ++k) {
    // corner base addrs for this tap (s1 = idx&3, s2 = (idx>>2)&1 derivable from idx)
    const unsigned wA = posA[k], wB = posB[k];
    const unsigned i00 = wA & 0xFFFFu, i01 = wA >> 16;
    const unsigned i10 = wB & 0xFFFFu, i11 = wB >> 16;
    const int b00 = (int)((i00 << 8) + (((unsigned)q ^ (i00 & 3)) << 4) + (((i00 >> 2) & 1) << 6));
    const int b01 = (int)((i01 << 8) + (((unsigned)q ^ (i01 & 3)) << 4) + (((i01 >> 2) & 1) << 6));
    const int b10 = (int)((i10 << 8) + (((unsigned)q ^ (i10 & 3)) << 4) + (((i10 >> 2) & 1) << 6));
    const int b11 = (int)((i11 << 8) + (((unsigned)q ^ (i11 & 3)) << 4) + (((i11 >> 2) & 1) << 6));
    const f16x4 wv = wts[k];
    const f16x2 wp0 = {wv.x, wv.x}, wp1 = {wv.y, wv.y};
    const f16x2 wp2 = {wv.z, wv.z}, wp3 = {wv.w, wv.w};
    #pragma unroll
    for (int c4 = 0; c4 < 4; ++c4) {
      const int ch = k * 4 + c4;
      if (ch < 35)   // stage A(ch+1) into the other buffer (8 segs by 8 waves)
        gload_lds16(wsB + (ch + 1) * 4096 + wid * 512 + lane * 8,
                    s_a + ((ch + 1) & 1) * 4096 + wid * 512);
      const int cx = c4 << 6;
      union { uint4 u; f16x2 h[4]; } d0, d1, d2, d3;
      d0.u = *(const uint4*)(win + (b00 ^ cx));
      d1.u = *(const uint4*)(win + (b01 ^ cx));
      d2.u = *(const uint4*)(win + (b10 ^ cx));
      d3.u = *(const uint4*)(win + (b11 ^ cx));
      union { f16x2 h[4]; f16x8 v; } bf;
      #pragma unroll
      for (int i = 0; i < 4; ++i) {
        f16x2 s = d0.h[i] * wp0;
        s = s + d1.h[i] * wp1;
        s = s + d2.h[i] * wp2;
        s = s + d3.h[i] * wp3;
        bf.h[i] = s;
      }
      const f16* ab = s_a + (ch & 1) * 4096;
      #pragma unroll
      for (int mt = 0; mt < 8; ++mt) {
        f16x8 a = *(const f16x8*)&ab[mt * 512 + lane * 8];
        acc[mt] = __builtin_amdgcn_mfma_f32_16x16x32_f16(a, bf.v, acc[mt], 0, 0, 0);
      }
      __syncthreads();   // drain A staging + protect dbuf swap
    }
  }

  float* o = out + (size_t)b * 128 * 4096 + rowy * 64 + px;
  #pragma unroll
  for (int mt = 0; mt < 8; ++mt) {
    #pragma unroll
    for (int r = 0; r < 4; ++r) {
      int oc = mt * 16 + q * 4 + r;
      o[oc * 4096] = acc[mt][r] + b_def[oc];
    }
  }
}

extern "C" void kernel_launch(void* const* d_in, const int* in_sizes, int n_in,
                              void* d_out, int out_size, void* d_ws, size_t ws_size,
                              hipStream_t stream) {
  const float* x     = (const float*)d_in[0];
  const float* w_off = (const float*)d_in[1];
  const float* b_off = (const float*)d_in[2];
  const float* w_def = (const float*)d_in[3];
  const float* b_def = (const float*)d_in[4];
  float* out = (float*)d_out;

  f16* wsA = (f16*)d_ws;
  f16* wsB = (f16*)((char*)d_ws + OFF_WSB);
  f16* xt  = (f16*)((char*)d_ws + OFF_XT);

  static int smem_opted = 0;
  if (!smem_opted) {
    hipFuncSetAttribute((const void*)fused_dcn_kernel,
                        hipFuncAttributeMaxDynamicSharedMemorySize, SMEM_BYTES);
    smem_opted = 1;
  }

  prep_transpose_kernel<<<dim3(PREP_BLOCKS + NBATCH * 64), dim3(256), 0, stream>>>(
      w_off, w_def, wsA, wsB, x, xt);
  fused_dcn_kernel<<<dim3(NBATCH * 32), dim3(512), SMEM_BYTES, stream>>>(
      xt, wsA, wsB, b_off, b_def, out);
}